// Round 13
// baseline (200.740 us; speedup 1.0000x reference)
//
#include <hip/hip_runtime.h>
#include <cfloat>

#define N_TOK 8192
#define DIM 512
#define KCODES 1024
#define LEVELS 3

// d_out float offsets
#define OUT_CODES (N_TOK*DIM)
#define OUT_COMMIT (OUT_CODES + N_TOK*LEVELS)
#define OUT_USAGE (OUT_COMMIT + 1)

// ws float offsets (small region)
#define WS_C2 0
#define WS_PROBS 3072
#define WS_COMMIT 6144
#define NBLK_B 2048
#define WS_SMALL_BYTES 49152
// byte offsets (large region)
#define WS_CBH_BYTES 81920
#define WS_CBL_BYTES (WS_CBH_BYTES + (size_t)LEVELS*KCODES*DIM*2)

// A LDS row stride in f16. 536 (not 520): pushes total LDS to 83232 B so TWO 16-wave
// blocks cannot co-reside (2x83232 > 163840) -> compiler's occupancy heuristic targets
// 1 block/CU = 4 waves/EU -> 128-VGPR budget instead of 64 (R11/R12 spilled at 64).
// Bank profile identical to 520: stride mod 32 words = 12 vs 4, both alias only lanes
// 8 apart = 2-way conflict = free.
#define APAD 536

typedef _Float16 f16x8 __attribute__((ext_vector_type(8)));
typedef _Float16 f16x4v __attribute__((ext_vector_type(4)));
typedef float f32x4 __attribute__((ext_vector_type(4)));

// ---------------------------------------------------------------- c2 = ||cb_k||^2
__global__ void c2_kernel(const float* __restrict__ cb, float* __restrict__ ws) {
  int row = blockIdx.x * 4 + (threadIdx.x >> 6);   // 0..3071
  int lane = threadIdx.x & 63;
  const float* p = cb + (size_t)row * DIM;
  float s = 0.f;
  #pragma unroll
  for (int j = 0; j < DIM/64; ++j) { float v = p[lane + 64*j]; s = fmaf(v, v, s); }
  #pragma unroll
  for (int m = 32; m; m >>= 1) s += __shfl_xor(s, m, 64);
  if (lane == 0) ws[WS_C2 + row] = s;
}

// ---------------------------------------------------------------- cb f32 -> f16 hi/lo split,
// packed in MFMA-fragment order: [level][kk (K/32)][tile (64 = 16 codes)][lane 64][8 f16].
__global__ void split_kernel(const float* __restrict__ cb,
                             _Float16* __restrict__ ch, _Float16* __restrict__ cl) {
  int idx = blockIdx.x * 256 + threadIdx.x;        // 0..196607
  int l = idx & 63;
  int t = (idx >> 6) & 63;
  int kk = (idx >> 12) & 15;
  int lev = idx >> 16;
  int code = t * 16 + (l & 15);
  int d0 = kk * 32 + (l >> 4) * 8;
  const float* src = cb + ((size_t)lev * KCODES + code) * DIM + d0;
  f16x8 h, lo;
  #pragma unroll
  for (int j = 0; j < 8; ++j) {
    float v = src[j];
    _Float16 hh = (_Float16)v;
    h[j] = hh;
    lo[j] = (_Float16)(v - (float)hh);
  }
  *(f16x8*)(ch + (size_t)idx * 8) = h;
  *(f16x8*)(cl + (size_t)idx * 8) = lo;
}

// forced-residency global load: SGPR base + 32b VGPR offset (coalesced)
__device__ __forceinline__ uint4 gld(const _Float16* base, unsigned voff) {
  uint4 r;
  asm volatile("global_load_dwordx4 %0, %1, %2 offset:0"
               : "=v"(r) : "v"(voff), "s"(base));
  return r;
}

#define WAITV(N) asm volatile("s_waitcnt vmcnt(" #N ")");
#define SB __builtin_amdgcn_sched_barrier(0x3F7);   // block only MFMA from crossing

// ---------------------------------------------------------------- fused level kernel
// R12 structure (validated): 1024 threads = 16 waves, each wave owns 64 codes (4 tiles);
// block = 32 tokens x 1024 codes; waves/SIMD = 4 to cover L3-hit latency.
// FIX vs R12: amdgpu_waves_per_eu(4,4) + LDS pad (APAD 536) force the 128-VGPR budget
// (grid = 256 = 1 block/CU, so the 2-block/64-VGPR target R11/R12 compiled for can
// never materialize -- it only caused scratch spills).
__global__ void __launch_bounds__(1024, 1)
__attribute__((amdgpu_waves_per_eu(4, 4)))
rvq_fused_kernel(const float* __restrict__ x,
                 float* __restrict__ qsum,
                 const _Float16* __restrict__ cbh,
                 const _Float16* __restrict__ cbl,
                 const float* __restrict__ cbf,
                 const float* __restrict__ c2,
                 float* __restrict__ probs_g,
                 float* __restrict__ codes_out,
                 float* __restrict__ partials,
                 int level)
{
  __shared__ _Float16 Ah[32*APAD];
  __shared__ _Float16 Al[32*APAD];
  __shared__ float c2s[KCODES];
  __shared__ float probs_lds[KCODES];
  __shared__ float x2s[32];
  __shared__ float wredd[16][32];
  __shared__ int   wredi[16][32];
  __shared__ float wredz[16][32];
  __shared__ int   fcode[32];
  __shared__ float wpart[8];

  const int tid = threadIdx.x;
  const int w = tid >> 6, l = tid & 63;
  const int l15 = l & 15, l4 = l >> 4;
  const int tok0 = blockIdx.x * 32;
  const int slab = w * 64;                 // 16 waves x 64 codes

  for (int i = tid; i < KCODES; i += 1024) { c2s[i] = c2[i]; probs_lds[i] = 0.f; }

  // ---- one-time A staging (first 512 threads; R10 code verbatim -> bitwise x2/residual)
  if (tid < 512) {
    const int srow = tid >> 4;          // 0..31
    const int sc4 = (tid & 15) * 4;     // float4 col base
    const float* xr_s = x + (size_t)(tok0 + srow) * DIM;
    const float* qr_s = qsum + (size_t)(tok0 + srow) * DIM;
    float x2p = 0.f;
    #pragma unroll
    for (int j = 0; j < 8; ++j) {
      int c = sc4 + j * 64;
      float4 xv = *(const float4*)(xr_s + c);
      float a0, a1, a2, a3;
      if (level) {
        float4 qv = *(const float4*)(qr_s + c);
        a0 = xv.x - qv.x; a1 = xv.y - qv.y; a2 = xv.z - qv.z; a3 = xv.w - qv.w;
      } else { a0 = xv.x; a1 = xv.y; a2 = xv.z; a3 = xv.w; }
      _Float16 h0 = (_Float16)a0, h1 = (_Float16)a1, h2 = (_Float16)a2, h3 = (_Float16)a3;
      f16x4v hv; hv[0] = h0; hv[1] = h1; hv[2] = h2; hv[3] = h3;
      f16x4v lv;
      lv[0] = (_Float16)(a0 - (float)h0);
      lv[1] = (_Float16)(a1 - (float)h1);
      lv[2] = (_Float16)(a2 - (float)h2);
      lv[3] = (_Float16)(a3 - (float)h3);
      *(f16x4v*)(&Ah[srow * APAD + c]) = hv;
      *(f16x4v*)(&Al[srow * APAD + c]) = lv;
      x2p = fmaf(a3, a3, fmaf(a2, a2, fmaf(a1, a1, fmaf(a0, a0, x2p))));
    }
    #pragma unroll
    for (int m = 1; m < 16; m <<= 1) x2p += __shfl_xor(x2p, m, 64);
    if ((tid & 15) == 0) x2s[srow] = x2p;
  }

  f32x4 acc[2][4];
  #pragma unroll
  for (int mt = 0; mt < 2; ++mt)
    #pragma unroll
    for (int nt = 0; nt < 4; ++nt) acc[mt][nt] = (f32x4){0.f, 0.f, 0.f, 0.f};

  // per-nt byte offsets into the packed level codebook: tile = w*4+nt, lane l
  unsigned boff[4];
  #pragma unroll
  for (int nt = 0; nt < 4; ++nt)
    boff[nt] = (unsigned)(((w * 4 + nt) * 64 + l) * 16);

  __syncthreads();   // staging + c2s init visible; NO barriers until epilogue

  // ---- K-loop: asm-pipelined B (dbuf b0/b1, 8 loads each), counted vmcnt, depth 1
  uint4 b0[8], b1[8];

  #define ISSUE(B, KK) { \
    const _Float16* hb = cbh + (size_t)(KK) * 32768; \
    const _Float16* lb = cbl + (size_t)(KK) * 32768; \
    _Pragma("unroll") \
    for (int nt = 0; nt < 4; ++nt) { \
      B[2*nt]   = gld(hb, boff[nt]); \
      B[2*nt+1] = gld(lb, boff[nt]); \
    } }

  #define STEPK(KK, B) { \
    f16x8 ah[2], al[2]; \
    _Pragma("unroll") \
    for (int mt = 0; mt < 2; ++mt) { \
      int o = (mt * 16 + l15) * APAD + (KK) * 32 + l4 * 8; \
      ah[mt] = *(const f16x8*)(&Ah[o]); \
      al[mt] = *(const f16x8*)(&Al[o]); \
    } \
    _Pragma("unroll") \
    for (int nt = 0; nt < 4; ++nt) { \
      f16x8 bh = __builtin_bit_cast(f16x8, B[2*nt]); \
      f16x8 bl = __builtin_bit_cast(f16x8, B[2*nt+1]); \
      _Pragma("unroll") \
      for (int mt = 0; mt < 2; ++mt) \
        acc[mt][nt] = __builtin_amdgcn_mfma_f32_16x16x32_f16(ah[mt], bh, acc[mt][nt], 0, 0, 0); \
      _Pragma("unroll") \
      for (int mt = 0; mt < 2; ++mt) \
        acc[mt][nt] = __builtin_amdgcn_mfma_f32_16x16x32_f16(ah[mt], bl, acc[mt][nt], 0, 0, 0); \
      _Pragma("unroll") \
      for (int mt = 0; mt < 2; ++mt) \
        acc[mt][nt] = __builtin_amdgcn_mfma_f32_16x16x32_f16(al[mt], bh, acc[mt][nt], 0, 0, 0); \
    } }

  ISSUE(b0, 0)
  ISSUE(b1, 1)   WAITV(8) SB STEPK(0,  b0)
  ISSUE(b0, 2)   WAITV(8) SB STEPK(1,  b1)
  ISSUE(b1, 3)   WAITV(8) SB STEPK(2,  b0)
  ISSUE(b0, 4)   WAITV(8) SB STEPK(3,  b1)
  ISSUE(b1, 5)   WAITV(8) SB STEPK(4,  b0)
  ISSUE(b0, 6)   WAITV(8) SB STEPK(5,  b1)
  ISSUE(b1, 7)   WAITV(8) SB STEPK(6,  b0)
  ISSUE(b0, 8)   WAITV(8) SB STEPK(7,  b1)
  ISSUE(b1, 9)   WAITV(8) SB STEPK(8,  b0)
  ISSUE(b0, 10)  WAITV(8) SB STEPK(9,  b1)
  ISSUE(b1, 11)  WAITV(8) SB STEPK(10, b0)
  ISSUE(b0, 12)  WAITV(8) SB STEPK(11, b1)
  ISSUE(b1, 13)  WAITV(8) SB STEPK(12, b0)
  ISSUE(b0, 14)  WAITV(8) SB STEPK(13, b1)
  ISSUE(b1, 15)  WAITV(8) SB STEPK(14, b0)
                 WAITV(0) SB STEPK(15, b1)
  #undef ISSUE
  #undef STEPK

  __syncthreads();

  // ---- epilogue: d2, argmin (first-index ties), softmax probs
  float c2v[4];
  #pragma unroll
  for (int nt = 0; nt < 4; ++nt) c2v[nt] = c2s[slab + nt * 16 + l15];

  // pass 1: per-wave argmin over this wave's 64 codes
  #pragma unroll
  for (int mt = 0; mt < 2; ++mt) {
    #pragma unroll
    for (int r = 0; r < 4; ++r) {
      int t = mt * 16 + l4 * 4 + r;
      float x2t = x2s[t];
      float best = FLT_MAX; int bc = 0x7fffffff;
      #pragma unroll
      for (int nt = 0; nt < 4; ++nt) {
        float t1 = x2t + c2v[nt];
        float d2 = t1 - 2.0f * acc[mt][nt][r];
        acc[mt][nt][r] = d2;
        int c = slab + nt * 16 + l15;
        if (d2 < best) { best = d2; bc = c; }   // ascending c per lane -> first wins
      }
      #pragma unroll
      for (int m = 1; m < 16; m <<= 1) {
        float ob = __shfl_xor(best, m, 64);
        int oc = __shfl_xor(bc, m, 64);
        if (ob < best || (ob == best && oc < bc)) { best = ob; bc = oc; }
      }
      if (l15 == 0) { wredd[w][t] = best; wredi[w][t] = bc; }
    }
  }
  __syncthreads();

  // pass 2: combine the 16 waves' partial argmins (ascending wave = ascending code)
  float bfin[2][4];
  #pragma unroll
  for (int mt = 0; mt < 2; ++mt) {
    #pragma unroll
    for (int r = 0; r < 4; ++r) {
      int t = mt * 16 + l4 * 4 + r;
      float best = FLT_MAX; int bc = 0x7fffffff;
      #pragma unroll
      for (int wv = 0; wv < 16; ++wv) {
        float ob = wredd[wv][t]; int oc = wredi[wv][t];
        if (ob < best || (ob == best && oc < bc)) { best = ob; bc = oc; }
      }
      bfin[mt][r] = best;
      if (w == 0 && l15 == 0) {
        fcode[t] = bc;
        codes_out[(size_t)(tok0 + t) * LEVELS + level] = (float)bc;
      }
    }
  }
  __syncthreads();

  // pass 3: Z = sum exp(d2min - d2)
  #pragma unroll
  for (int mt = 0; mt < 2; ++mt) {
    #pragma unroll
    for (int r = 0; r < 4; ++r) {
      int t = mt * 16 + l4 * 4 + r;
      float z = 0.f;
      #pragma unroll
      for (int nt = 0; nt < 4; ++nt) {
        float p = __expf(bfin[mt][r] - acc[mt][nt][r]);
        acc[mt][nt][r] = p;
        z += p;
      }
      #pragma unroll
      for (int m = 1; m < 16; m <<= 1) z += __shfl_xor(z, m, 64);
      if (l15 == 0) wredz[w][t] = z;
    }
  }
  __syncthreads();

  float zin[2][4];
  #pragma unroll
  for (int mt = 0; mt < 2; ++mt) {
    #pragma unroll
    for (int r = 0; r < 4; ++r) {
      int t = mt * 16 + l4 * 4 + r;
      float Z = 0.f;
      #pragma unroll
      for (int wv = 0; wv < 16; ++wv) Z += wredz[wv][t];
      zin[mt][r] = 1.0f / Z;
    }
  }
  __syncthreads();

  // probs accumulation: each wave owns its 64-code slab (no conflicts)
  #pragma unroll
  for (int nt = 0; nt < 4; ++nt) {
    float v = 0.f;
    #pragma unroll
    for (int mt = 0; mt < 2; ++mt)
      #pragma unroll
      for (int r = 0; r < 4; ++r) v = fmaf(acc[mt][nt][r], zin[mt][r], v);
    v += __shfl_xor(v, 16, 64);
    v += __shfl_xor(v, 32, 64);
    if (l4 == 0) probs_lds[slab + nt * 16 + l15] += v;
  }
  __syncthreads();
  for (int i = tid; i < KCODES; i += 1024) atomicAdd(&probs_g[i], probs_lds[i]);
  __syncthreads();

  // ---- fused update: qsum += cb[code]; commit partial (first 512 threads, R10 verbatim)
  if (tid < 512) {
    const int urow = tid >> 4;
    const int uc = (tid & 15) * 4;
    const int code = fcode[urow];
    const float* cbr = cbf + (size_t)code * DIM;
    const float* xr = x + (size_t)(tok0 + urow) * DIM;
    float* qr = qsum + (size_t)(tok0 + urow) * DIM;
    float sq = 0.f;
    #pragma unroll
    for (int j = 0; j < 8; ++j) {
      int d = uc + j * 64;
      float4 cv = *(const float4*)(cbr + d);
      float4 nv;
      if (level) {
        float4 qv = *(const float4*)(qr + d);
        nv = make_float4(qv.x + cv.x, qv.y + cv.y, qv.z + cv.z, qv.w + cv.w);
      } else nv = cv;
      *(float4*)(qr + d) = nv;
      float4 xv = *(const float4*)(xr + d);
      float a = xv.x - nv.x, b = xv.y - nv.y, c = xv.z - nv.z, e = xv.w - nv.w;
      sq = fmaf(a, a, sq); sq = fmaf(b, b, sq); sq = fmaf(c, c, sq); sq = fmaf(e, e, sq);
    }
    #pragma unroll
    for (int m = 32; m; m >>= 1) sq += __shfl_xor(sq, m, 64);
    if (l == 0) wpart[w] = sq;
  }
  __syncthreads();
  if (tid == 0) {
    float s = 0.f;
    #pragma unroll
    for (int i = 0; i < 8; ++i) s += wpart[i];
    partials[level * NBLK_B + blockIdx.x] = s;
  }
}

// ---------------------------------------------------------------- losses
__global__ void finalize_kernel(const float* __restrict__ ws, float* __restrict__ out) {
  const int tid = threadIdx.x;   // 1024 threads
  __shared__ float red[1024];
  float usum = 0.f, csum = 0.f;
  for (int lev = 0; lev < LEVELS; ++lev) {
    float a = ws[WS_PROBS + lev*KCODES + tid] * (1.0f/N_TOK);
    a = fmaxf(a, 1e-5f);
    red[tid] = a * logf(a);
    __syncthreads();
    for (int s = 512; s; s >>= 1) { if (tid < s) red[tid] += red[tid+s]; __syncthreads(); }
    if (tid == 0) usum += 6.9314718055994531f + red[0];
    __syncthreads();
    red[tid] = ws[WS_COMMIT + lev*NBLK_B + tid] + ws[WS_COMMIT + lev*NBLK_B + tid + 1024];
    __syncthreads();
    for (int s = 512; s; s >>= 1) { if (tid < s) red[tid] += red[tid+s]; __syncthreads(); }
    if (tid == 0) csum += red[0];
    __syncthreads();
  }
  if (tid == 0) {
    out[OUT_COMMIT] = (0.25f/3.0f) * (csum / (float)(N_TOK*DIM));
    out[OUT_USAGE]  = (1e-3f/3.0f) * usum;
  }
}

// ---------------------------------------------------------------- launch
extern "C" void kernel_launch(void* const* d_in, const int* in_sizes, int n_in,
                              void* d_out, int out_size, void* d_ws, size_t ws_size,
                              hipStream_t stream) {
  const float* x  = (const float*)d_in[0];
  const float* cb = (const float*)d_in[1];
  float* out = (float*)d_out;
  float* ws  = (float*)d_ws;

  // zero probs + commit-partial accumulators (c2 region harmlessly included)
  hipMemsetAsync(d_ws, 0, WS_SMALL_BYTES, stream);

  _Float16* cbh = (_Float16*)((char*)d_ws + WS_CBH_BYTES);
  _Float16* cbl = (_Float16*)((char*)d_ws + WS_CBL_BYTES);

  split_kernel<<<(LEVELS*16*64*64)/256, 256, 0, stream>>>(cb, cbh, cbl);
  c2_kernel<<<(LEVELS*KCODES)/4, 256, 0, stream>>>(cb, ws);

  for (int level = 0; level < LEVELS; ++level) {
    rvq_fused_kernel<<<N_TOK/32, 1024, 0, stream>>>(
        x, out,
        cbh + (size_t)level*KCODES*DIM, cbl + (size_t)level*KCODES*DIM,
        cb + (size_t)level*KCODES*DIM,
        ws + WS_C2 + level*KCODES, ws + WS_PROBS + level*KCODES,
        out + OUT_CODES, ws + WS_COMMIT, level);
  }
  finalize_kernel<<<1, 1024, 0, stream>>>(ws, out);
}

// Round 14
// 171.689 us; speedup vs baseline: 1.1692x; 1.1692x over previous
//
#include <hip/hip_runtime.h>
#include <cfloat>

#define N_TOK 8192
#define DIM 512
#define KCODES 1024
#define LEVELS 3

// d_out float offsets
#define OUT_CODES (N_TOK*DIM)
#define OUT_COMMIT (OUT_CODES + N_TOK*LEVELS)
#define OUT_USAGE (OUT_COMMIT + 1)

// ws float offsets (small region)
#define WS_C2 0
#define WS_PROBS 3072
#define WS_COMMIT 6144
#define NBLK_B 2048
#define WS_SMALL_BYTES 49152
// byte offsets (large region)
#define WS_CBH_BYTES 81920
#define WS_CBL_BYTES (WS_CBH_BYTES + (size_t)LEVELS*KCODES*DIM*2)

#define APAD 520   // A LDS row stride in f16

typedef _Float16 f16x8 __attribute__((ext_vector_type(8)));
typedef _Float16 f16x4v __attribute__((ext_vector_type(4)));
typedef float f32x4 __attribute__((ext_vector_type(4)));

// ---------------------------------------------------------------- c2 = ||cb_k||^2
__global__ void c2_kernel(const float* __restrict__ cb, float* __restrict__ ws) {
  int row = blockIdx.x * 4 + (threadIdx.x >> 6);   // 0..3071
  int lane = threadIdx.x & 63;
  const float* p = cb + (size_t)row * DIM;
  float s = 0.f;
  #pragma unroll
  for (int j = 0; j < DIM/64; ++j) { float v = p[lane + 64*j]; s = fmaf(v, v, s); }
  #pragma unroll
  for (int m = 32; m; m >>= 1) s += __shfl_xor(s, m, 64);
  if (lane == 0) ws[WS_C2 + row] = s;
}

// ---------------------------------------------------------------- cb f32 -> f16 hi/lo split,
// packed in MFMA-fragment order: [level][kk (K/32)][tile (64 = 16 codes)][lane 64][8 f16].
__global__ void split_kernel(const float* __restrict__ cb,
                             _Float16* __restrict__ ch, _Float16* __restrict__ cl) {
  int idx = blockIdx.x * 256 + threadIdx.x;        // 0..196607
  int l = idx & 63;
  int t = (idx >> 6) & 63;
  int kk = (idx >> 12) & 15;
  int lev = idx >> 16;
  int code = t * 16 + (l & 15);
  int d0 = kk * 32 + (l >> 4) * 8;
  const float* src = cb + ((size_t)lev * KCODES + code) * DIM + d0;
  f16x8 h, lo;
  #pragma unroll
  for (int j = 0; j < 8; ++j) {
    float v = src[j];
    _Float16 hh = (_Float16)v;
    h[j] = hh;
    lo[j] = (_Float16)(v - (float)hh);
  }
  *(f16x8*)(ch + (size_t)idx * 8) = h;
  *(f16x8*)(cl + (size_t)idx * 8) = lo;
}

// forced-residency global load: SGPR base + 32b VGPR offset (coalesced)
__device__ __forceinline__ uint4 gld(const _Float16* base, unsigned voff) {
  uint4 r;
  asm volatile("global_load_dwordx4 %0, %1, %2 offset:0"
               : "=v"(r) : "v"(voff), "s"(base));
  return r;
}

#define WAITV(N) asm volatile("s_waitcnt vmcnt(" #N ")");
#define SB __builtin_amdgcn_sched_barrier(0x3F7);   // block only MFMA from crossing

// ---------------------------------------------------------------- fused level kernel
// R10 structure (validated, 56us/level) + ONE change: per-block code-slab rotation.
// Wave w of block b works slab ws = (w + b/8) & 7 -- blocks round-robin across the
// 8 XCDs, so b/8 differs among blocks sharing an XCD-L2; rotating the slab start
// decorrelates the 32 per-CU read streams that otherwise hit the same L2 lines in
// lockstep (R10 ran at 53% of the per-XCD L2 BW ceiling). Per-(token,code) chains
// unchanged; cross-wave argmin is an order-independent lexicographic min -> codes
// bitwise identical.
__launch_bounds__(512, 2)
__global__ void rvq_fused_kernel(const float* __restrict__ x,
                                 float* __restrict__ qsum,
                                 const _Float16* __restrict__ cbh,
                                 const _Float16* __restrict__ cbl,
                                 const float* __restrict__ cbf,
                                 const float* __restrict__ c2,
                                 float* __restrict__ probs_g,
                                 float* __restrict__ codes_out,
                                 float* __restrict__ partials,
                                 int level)
{
  __shared__ _Float16 Ah[32*APAD];
  __shared__ _Float16 Al[32*APAD];
  __shared__ float c2s[KCODES];
  __shared__ float probs_lds[KCODES];
  __shared__ float x2s[32];
  __shared__ float wredd[8][32];
  __shared__ int   wredi[8][32];
  __shared__ float wredz[8][32];
  __shared__ int   fcode[32];
  __shared__ float wpart[8];

  const int tid = threadIdx.x;
  const int w = tid >> 6, l = tid & 63;
  const int l15 = l & 15, l4 = l >> 4;
  const int tok0 = blockIdx.x * 32;
  const int ws_rot = (w + (blockIdx.x >> 3)) & 7;   // rotated code-group for this wave
  const int slab = ws_rot * 128;

  for (int i = tid; i < KCODES; i += 512) { c2s[i] = c2[i]; probs_lds[i] = 0.f; }

  // ---- one-time A staging: residual hi/lo split -> LDS, fused x2
  {
    const int srow = tid >> 4;          // 0..31
    const int sc4 = (tid & 15) * 4;     // float4 col base
    const float* xr_s = x + (size_t)(tok0 + srow) * DIM;
    const float* qr_s = qsum + (size_t)(tok0 + srow) * DIM;
    float x2p = 0.f;
    #pragma unroll
    for (int j = 0; j < 8; ++j) {
      int c = sc4 + j * 64;
      float4 xv = *(const float4*)(xr_s + c);
      float a0, a1, a2, a3;
      if (level) {
        float4 qv = *(const float4*)(qr_s + c);
        a0 = xv.x - qv.x; a1 = xv.y - qv.y; a2 = xv.z - qv.z; a3 = xv.w - qv.w;
      } else { a0 = xv.x; a1 = xv.y; a2 = xv.z; a3 = xv.w; }
      _Float16 h0 = (_Float16)a0, h1 = (_Float16)a1, h2 = (_Float16)a2, h3 = (_Float16)a3;
      f16x4v hv; hv[0] = h0; hv[1] = h1; hv[2] = h2; hv[3] = h3;
      f16x4v lv;
      lv[0] = (_Float16)(a0 - (float)h0);
      lv[1] = (_Float16)(a1 - (float)h1);
      lv[2] = (_Float16)(a2 - (float)h2);
      lv[3] = (_Float16)(a3 - (float)h3);
      *(f16x4v*)(&Ah[srow * APAD + c]) = hv;
      *(f16x4v*)(&Al[srow * APAD + c]) = lv;
      x2p = fmaf(a3, a3, fmaf(a2, a2, fmaf(a1, a1, fmaf(a0, a0, x2p))));
    }
    #pragma unroll
    for (int m = 1; m < 16; m <<= 1) x2p += __shfl_xor(x2p, m, 64);
    if ((tid & 15) == 0) x2s[srow] = x2p;
  }

  f32x4 acc[2][8];
  #pragma unroll
  for (int mt = 0; mt < 2; ++mt)
    #pragma unroll
    for (int nt = 0; nt < 8; ++nt) acc[mt][nt] = (f32x4){0.f, 0.f, 0.f, 0.f};

  // per-nt byte offsets into the packed level codebook: tile = ws_rot*8+nt, lane l
  unsigned boff[8];
  #pragma unroll
  for (int nt = 0; nt < 8; ++nt)
    boff[nt] = (unsigned)(((ws_rot * 8 + nt) * 64 + l) * 16);

  __syncthreads();   // staging + c2s init visible; NO barriers until epilogue

  // ---- K-loop: asm-pipelined B (dbuf b0/b1), counted vmcnt, depth 1
  uint4 b0[16], b1[16];

  #define ISSUE(B, KK) { \
    const _Float16* hb = cbh + (size_t)(KK) * 32768; \
    const _Float16* lb = cbl + (size_t)(KK) * 32768; \
    _Pragma("unroll") \
    for (int nt = 0; nt < 8; ++nt) { \
      B[2*nt]   = gld(hb, boff[nt]); \
      B[2*nt+1] = gld(lb, boff[nt]); \
    } }

  #define STEPK(KK, B) { \
    f16x8 ah[2], al[2]; \
    _Pragma("unroll") \
    for (int mt = 0; mt < 2; ++mt) { \
      int o = (mt * 16 + l15) * APAD + (KK) * 32 + l4 * 8; \
      ah[mt] = *(const f16x8*)(&Ah[o]); \
      al[mt] = *(const f16x8*)(&Al[o]); \
    } \
    _Pragma("unroll") \
    for (int nt = 0; nt < 8; ++nt) { \
      f16x8 bh = __builtin_bit_cast(f16x8, B[2*nt]); \
      f16x8 bl = __builtin_bit_cast(f16x8, B[2*nt+1]); \
      _Pragma("unroll") \
      for (int mt = 0; mt < 2; ++mt) \
        acc[mt][nt] = __builtin_amdgcn_mfma_f32_16x16x32_f16(ah[mt], bh, acc[mt][nt], 0, 0, 0); \
      _Pragma("unroll") \
      for (int mt = 0; mt < 2; ++mt) \
        acc[mt][nt] = __builtin_amdgcn_mfma_f32_16x16x32_f16(ah[mt], bl, acc[mt][nt], 0, 0, 0); \
      _Pragma("unroll") \
      for (int mt = 0; mt < 2; ++mt) \
        acc[mt][nt] = __builtin_amdgcn_mfma_f32_16x16x32_f16(al[mt], bh, acc[mt][nt], 0, 0, 0); \
    } }

  ISSUE(b0, 0)
  ISSUE(b1, 1)   WAITV(16) SB STEPK(0,  b0)
  ISSUE(b0, 2)   WAITV(16) SB STEPK(1,  b1)
  ISSUE(b1, 3)   WAITV(16) SB STEPK(2,  b0)
  ISSUE(b0, 4)   WAITV(16) SB STEPK(3,  b1)
  ISSUE(b1, 5)   WAITV(16) SB STEPK(4,  b0)
  ISSUE(b0, 6)   WAITV(16) SB STEPK(5,  b1)
  ISSUE(b1, 7)   WAITV(16) SB STEPK(6,  b0)
  ISSUE(b0, 8)   WAITV(16) SB STEPK(7,  b1)
  ISSUE(b1, 9)   WAITV(16) SB STEPK(8,  b0)
  ISSUE(b0, 10)  WAITV(16) SB STEPK(9,  b1)
  ISSUE(b1, 11)  WAITV(16) SB STEPK(10, b0)
  ISSUE(b0, 12)  WAITV(16) SB STEPK(11, b1)
  ISSUE(b1, 13)  WAITV(16) SB STEPK(12, b0)
  ISSUE(b0, 14)  WAITV(16) SB STEPK(13, b1)
  ISSUE(b1, 15)  WAITV(16) SB STEPK(14, b0)
                 WAITV(0)  SB STEPK(15, b1)
  #undef ISSUE
  #undef STEPK

  __syncthreads();

  // ---- epilogue: d2, argmin (first-index ties), softmax probs
  float c2v[8];
  #pragma unroll
  for (int nt = 0; nt < 8; ++nt) c2v[nt] = c2s[slab + nt * 16 + l15];

  // pass 1: per-wave argmin over this wave's 128 codes
  #pragma unroll
  for (int mt = 0; mt < 2; ++mt) {
    #pragma unroll
    for (int r = 0; r < 4; ++r) {
      int t = mt * 16 + l4 * 4 + r;
      float x2t = x2s[t];
      float best = FLT_MAX; int bc = 0x7fffffff;
      #pragma unroll
      for (int nt = 0; nt < 8; ++nt) {
        float t1 = x2t + c2v[nt];
        float d2 = t1 - 2.0f * acc[mt][nt][r];
        acc[mt][nt][r] = d2;
        int c = slab + nt * 16 + l15;
        if (d2 < best) { best = d2; bc = c; }   // ascending c per lane -> first wins
      }
      #pragma unroll
      for (int m = 1; m < 16; m <<= 1) {
        float ob = __shfl_xor(best, m, 64);
        int oc = __shfl_xor(bc, m, 64);
        if (ob < best || (ob == best && oc < bc)) { best = ob; bc = oc; }
      }
      if (l15 == 0) { wredd[w][t] = best; wredi[w][t] = bc; }
    }
  }
  __syncthreads();

  // pass 2: combine the 8 waves' partial argmins (lexicographic min -- order-independent)
  float bfin[2][4];
  #pragma unroll
  for (int mt = 0; mt < 2; ++mt) {
    #pragma unroll
    for (int r = 0; r < 4; ++r) {
      int t = mt * 16 + l4 * 4 + r;
      float best = FLT_MAX; int bc = 0x7fffffff;
      #pragma unroll
      for (int wv = 0; wv < 8; ++wv) {
        float ob = wredd[wv][t]; int oc = wredi[wv][t];
        if (ob < best || (ob == best && oc < bc)) { best = ob; bc = oc; }
      }
      bfin[mt][r] = best;
      if (w == 0 && l15 == 0) {
        fcode[t] = bc;
        codes_out[(size_t)(tok0 + t) * LEVELS + level] = (float)bc;
      }
    }
  }
  __syncthreads();

  // pass 3: Z = sum exp(d2min - d2)
  #pragma unroll
  for (int mt = 0; mt < 2; ++mt) {
    #pragma unroll
    for (int r = 0; r < 4; ++r) {
      int t = mt * 16 + l4 * 4 + r;
      float z = 0.f;
      #pragma unroll
      for (int nt = 0; nt < 8; ++nt) {
        float p = __expf(bfin[mt][r] - acc[mt][nt][r]);
        acc[mt][nt][r] = p;
        z += p;
      }
      #pragma unroll
      for (int m = 1; m < 16; m <<= 1) z += __shfl_xor(z, m, 64);
      if (l15 == 0) wredz[w][t] = z;
    }
  }
  __syncthreads();

  float zin[2][4];
  #pragma unroll
  for (int mt = 0; mt < 2; ++mt) {
    #pragma unroll
    for (int r = 0; r < 4; ++r) {
      int t = mt * 16 + l4 * 4 + r;
      float Z = 0.f;
      #pragma unroll
      for (int wv = 0; wv < 8; ++wv) Z += wredz[wv][t];
      zin[mt][r] = 1.0f / Z;
    }
  }
  __syncthreads();

  // probs accumulation: each wave owns its 128-code slab (rotation is a permutation
  // of slabs across waves -> still conflict-free)
  #pragma unroll
  for (int nt = 0; nt < 8; ++nt) {
    float v = 0.f;
    #pragma unroll
    for (int mt = 0; mt < 2; ++mt)
      #pragma unroll
      for (int r = 0; r < 4; ++r) v = fmaf(acc[mt][nt][r], zin[mt][r], v);
    v += __shfl_xor(v, 16, 64);
    v += __shfl_xor(v, 32, 64);
    if (l4 == 0) probs_lds[slab + nt * 16 + l15] += v;
  }
  __syncthreads();
  for (int i = tid; i < KCODES; i += 512) atomicAdd(&probs_g[i], probs_lds[i]);
  __syncthreads();

  // ---- fused update: qsum += cb[code]; commit partial
  {
    const int urow = tid >> 4;
    const int uc = (tid & 15) * 4;
    const int code = fcode[urow];
    const float* cbr = cbf + (size_t)code * DIM;
    const float* xr = x + (size_t)(tok0 + urow) * DIM;
    float* qr = qsum + (size_t)(tok0 + urow) * DIM;
    float sq = 0.f;
    #pragma unroll
    for (int j = 0; j < 8; ++j) {
      int d = uc + j * 64;
      float4 cv = *(const float4*)(cbr + d);
      float4 nv;
      if (level) {
        float4 qv = *(const float4*)(qr + d);
        nv = make_float4(qv.x + cv.x, qv.y + cv.y, qv.z + cv.z, qv.w + cv.w);
      } else nv = cv;
      *(float4*)(qr + d) = nv;
      float4 xv = *(const float4*)(xr + d);
      float a = xv.x - nv.x, b = xv.y - nv.y, c = xv.z - nv.z, e = xv.w - nv.w;
      sq = fmaf(a, a, sq); sq = fmaf(b, b, sq); sq = fmaf(c, c, sq); sq = fmaf(e, e, sq);
    }
    #pragma unroll
    for (int m = 32; m; m >>= 1) sq += __shfl_xor(sq, m, 64);
    if (l == 0) wpart[w] = sq;
    __syncthreads();
    if (tid == 0) {
      float s = 0.f;
      #pragma unroll
      for (int i = 0; i < 8; ++i) s += wpart[i];
      partials[level * NBLK_B + blockIdx.x] = s;
    }
  }
}

// ---------------------------------------------------------------- losses
__global__ void finalize_kernel(const float* __restrict__ ws, float* __restrict__ out) {
  const int tid = threadIdx.x;   // 1024 threads
  __shared__ float red[1024];
  float usum = 0.f, csum = 0.f;
  for (int lev = 0; lev < LEVELS; ++lev) {
    float a = ws[WS_PROBS + lev*KCODES + tid] * (1.0f/N_TOK);
    a = fmaxf(a, 1e-5f);
    red[tid] = a * logf(a);
    __syncthreads();
    for (int s = 512; s; s >>= 1) { if (tid < s) red[tid] += red[tid+s]; __syncthreads(); }
    if (tid == 0) usum += 6.9314718055994531f + red[0];
    __syncthreads();
    red[tid] = ws[WS_COMMIT + lev*NBLK_B + tid] + ws[WS_COMMIT + lev*NBLK_B + tid + 1024];
    __syncthreads();
    for (int s = 512; s; s >>= 1) { if (tid < s) red[tid] += red[tid+s]; __syncthreads(); }
    if (tid == 0) csum += red[0];
    __syncthreads();
  }
  if (tid == 0) {
    out[OUT_COMMIT] = (0.25f/3.0f) * (csum / (float)(N_TOK*DIM));
    out[OUT_USAGE]  = (1e-3f/3.0f) * usum;
  }
}

// ---------------------------------------------------------------- launch
extern "C" void kernel_launch(void* const* d_in, const int* in_sizes, int n_in,
                              void* d_out, int out_size, void* d_ws, size_t ws_size,
                              hipStream_t stream) {
  const float* x  = (const float*)d_in[0];
  const float* cb = (const float*)d_in[1];
  float* out = (float*)d_out;
  float* ws  = (float*)d_ws;

  // zero probs + commit-partial accumulators (c2 region harmlessly included)
  hipMemsetAsync(d_ws, 0, WS_SMALL_BYTES, stream);

  _Float16* cbh = (_Float16*)((char*)d_ws + WS_CBH_BYTES);
  _Float16* cbl = (_Float16*)((char*)d_ws + WS_CBL_BYTES);

  split_kernel<<<(LEVELS*16*64*64)/256, 256, 0, stream>>>(cb, cbh, cbl);
  c2_kernel<<<(LEVELS*KCODES)/4, 256, 0, stream>>>(cb, ws);

  for (int level = 0; level < LEVELS; ++level) {
    rvq_fused_kernel<<<N_TOK/32, 512, 0, stream>>>(
        x, out,
        cbh + (size_t)level*KCODES*DIM, cbl + (size_t)level*KCODES*DIM,
        cb + (size_t)level*KCODES*DIM,
        ws + WS_C2 + level*KCODES, ws + WS_PROBS + level*KCODES,
        out + OUT_CODES, ws + WS_COMMIT, level);
  }
  finalize_kernel<<<1, 1024, 0, stream>>>(ws, out);
}